// Round 15
// baseline (128.408 us; speedup 1.0000x reference)
//
#include <hip/hip_runtime.h>
#include <hip/hip_fp16.h>
#include <math.h>

#define NS_ 50000
#define NW_ 50000
#define IN_DIM_ 128
#define OUT_DIM_ 64

#define NSLAB 512          // partition slabs; slab_e = 3125 for E=1.6M
#define NB 1563            // buckets = ceil(NW/32), bucket = dst >> 5
#define CAPS 1280          // per-bucket capacity (mean 1024, +8 sigma; verified R11-R14)
#define CAPP 2304          // padded sorted capacity (<= 1280 + 31*32)

typedef _Float16 h16x8 __attribute__((ext_vector_type(8)));
typedef float f32x4 __attribute__((ext_vector_type(4)));

__device__ inline float leaky01(float x) { return x > 0.0f ? x : 0.01f * x; }

// Pack W into fp16 B-frag order (global, L2-resident) and wv128 = W @ wa.
__global__ __launch_bounds__(256) void prep_kernel(const float* __restrict__ Wfc,
                                                   const float* __restrict__ w_attn,
                                                   __half* __restrict__ W16f,
                                                   float* __restrict__ wv128) {
    int tid = threadIdx.x;
    for (int i = tid; i < IN_DIM_ * OUT_DIM_; i += 256) {
        int k = i >> 6, c = i & 63;
        int ni = c >> 4, c16 = c & 15, kstep = k >> 5, ks = (k & 31) >> 3, el = k & 7;
        W16f[(((ni * 4 + kstep) * 64) + ks * 16 + c16) * 8 + el] = __float2half(Wfc[i]);
    }
    if (tid < IN_DIM_) {
        float s = 0.f;
        for (int c = 0; c < OUT_DIM_; ++c) s += Wfc[tid * OUT_DIM_ + c] * w_attn[c];
        wv128[tid] = s;
    }
}

// MFMA fc: 64 rows/block, 4 waves (verified R14).
__global__ __launch_bounds__(256) void fc_kernel(const float* __restrict__ h,
                                                 const __half* __restrict__ W16f,
                                                 const float* __restrict__ wv128,
                                                 __half* __restrict__ z16,
                                                 float* __restrict__ t) {
    __shared__ __align__(16) __half Afrag[8192];
    __shared__ float ztile[64][68];
    int tid = threadIdx.x;
    int lane = tid & 63;
    int wv = tid >> 6;
    int row0 = blockIdx.x * 64;

    int k0 = (tid & 31) * 4;
    float4 wvv = *(const float4*)(wv128 + k0);
    int kstep = k0 >> 5, ks = (k0 & 31) >> 3, el = k0 & 7;
#pragma unroll
    for (int iter = 0; iter < 8; ++iter) {
        int r = (tid >> 5) + iter * 8;
        int row = row0 + r;
        float4 hv = (row < NS_) ? *(const float4*)(h + (size_t)row * IN_DIM_ + k0)
                                : make_float4(0.f, 0.f, 0.f, 0.f);
        int slot = ((r >> 4) * 4 + kstep) * 64 + ks * 16 + (r & 15);
        int slw = slot ^ ((slot >> 4) & 7);
        __half2 lo = __floats2half2_rn(hv.x, hv.y);
        __half2 hi = __floats2half2_rn(hv.z, hv.w);
        uint2 pk = make_uint2(*(unsigned*)&lo, *(unsigned*)&hi);
        *(uint2*)(&Afrag[slw * 8 + el]) = pk;
        float pt = hv.x * wvv.x + hv.y * wvv.y + hv.z * wvv.z + hv.w * wvv.w;
        pt += __shfl_down(pt, 16, 64);
        pt += __shfl_down(pt, 8, 64);
        pt += __shfl_down(pt, 4, 64);
        pt += __shfl_down(pt, 2, 64);
        pt += __shfl_down(pt, 1, 64);
        if ((tid & 31) == 0 && row < NS_) t[row] = pt;
    }
    __syncthreads();

    h16x8 af[4];
#pragma unroll
    for (int kst = 0; kst < 4; ++kst) {
        int s = (wv * 4 + kst) * 64 + lane;
        int sr = s ^ ((s >> 4) & 7);
        af[kst] = *(const h16x8*)(&Afrag[sr * 8]);
    }
#pragma unroll
    for (int ni = 0; ni < 4; ++ni) {
        f32x4 acc = {0.f, 0.f, 0.f, 0.f};
#pragma unroll
        for (int kst = 0; kst < 4; ++kst) {
            h16x8 bf = *(const h16x8*)(W16f + ((size_t)(ni * 4 + kst) * 64 + lane) * 8);
            acc = __builtin_amdgcn_mfma_f32_16x16x32_f16(af[kst], bf, acc, 0, 0, 0);
        }
        int col = ni * 16 + (lane & 15);
        int rb = wv * 16 + (lane >> 4) * 4;
        ztile[rb + 0][col] = acc[0];
        ztile[rb + 1][col] = acc[1];
        ztile[rb + 2][col] = acc[2];
        ztile[rb + 3][col] = acc[3];
    }
    __syncthreads();

    int nrows = NS_ - row0; if (nrows > 64) nrows = 64;
    for (int j = tid; j < 64 * 32; j += 256) {
        int r = j >> 5, c0 = (j & 31) * 2;
        if (r < nrows) {
            __half2 hp = __floats2half2_rn(ztile[r][c0], ztile[r][c0 + 1]);
            *(__half2*)(z16 + (size_t)(row0 + r) * OUT_DIM_ + c0) = hp;
        }
    }
}

// P1: per-slab hist + slab-local bucket-sorted scatter (as R14) + global btot.
__global__ __launch_bounds__(1024) void partition_kernel(const float* __restrict__ weight,
                                                         const int* __restrict__ src,
                                                         const int* __restrict__ dst,
                                                         const float* __restrict__ t,
                                                         unsigned* __restrict__ meta_sb,
                                                         int* __restrict__ btot,
                                                         int2* __restrict__ edata,
                                                         int E, int slab_e) {
    __shared__ int hist[NB];
    __shared__ int cur[NB];
    __shared__ int wsum[16];
    int tid = threadIdx.x;
    int lane = tid & 63;
    int wv = tid >> 6;
    int s = blockIdx.x;
    int e0 = s * slab_e;
    int e1 = e0 + slab_e; if (e1 > E) e1 = E;
    int cnt = e1 - e0;

    for (int i = tid; i < NB; i += 1024) hist[i] = 0;
    __syncthreads();

    float exr0 = 0, exr1 = 0, exr2 = 0, exr3 = 0;
    int mr0 = 0, mr1 = 0, mr2 = 0, mr3 = 0;
#define PART_LOAD(P, EXR, MR)                                              \
    {                                                                      \
        int i = tid + (P) * 1024;                                          \
        if (i < cnt) {                                                     \
            int e = e0 + i;                                                \
            int sr = src[e];                                               \
            int d = dst[e];                                                \
            float ev = weight[e] * leaky01(t[sr]);                         \
            EXR = __expf(ev);                                              \
            MR = sr | ((d & 31) << 16) | ((d >> 5) << 21);                 \
            atomicAdd(&hist[d >> 5], 1);                                   \
        }                                                                  \
    }
    PART_LOAD(0, exr0, mr0)
    PART_LOAD(1, exr1, mr1)
    PART_LOAD(2, exr2, mr2)
    PART_LOAD(3, exr3, mr3)
#undef PART_LOAD
    __syncthreads();

    int i0 = 2 * tid, i1 = 2 * tid + 1;
    int h0 = (i0 < NB) ? hist[i0] : 0;
    int h1 = (i1 < NB) ? hist[i1] : 0;
    int pairv = h0 + h1;
    int incl = pairv;
#pragma unroll
    for (int off = 1; off < 64; off <<= 1) {
        int u = __shfl_up(incl, off, 64);
        if (lane >= off) incl += u;
    }
    if (lane == 63) wsum[wv] = incl;
    __syncthreads();
    int woff = 0;
    for (int w = 0; w < wv; ++w) woff += wsum[w];
    incl += woff;
    int base = incl - pairv;
    if (i0 < NB) {
        cur[i0] = base;
        meta_sb[(size_t)s * NB + i0] = ((unsigned)h0 << 16) | (unsigned)base;
        if (h0 > 0) atomicAdd(&btot[i0], h0);
    }
    if (i1 < NB) {
        int b1 = base + h0;
        cur[i1] = b1;
        meta_sb[(size_t)s * NB + i1] = ((unsigned)h1 << 16) | (unsigned)b1;
        if (h1 > 0) atomicAdd(&btot[i1], h1);
    }
    __syncthreads();

#define PART_STORE(P, EXR, MR)                                             \
    {                                                                      \
        int i = tid + (P) * 1024;                                          \
        if (i < cnt) {                                                     \
            int b = ((unsigned)MR) >> 21;                                  \
            int pos = atomicAdd(&cur[b], 1);                               \
            edata[e0 + pos] = make_int2(__float_as_int(EXR), MR & 0x1FFFFF); \
        }                                                                  \
    }
    PART_STORE(0, exr0, mr0)
    PART_STORE(1, exr1, mr1)
    PART_STORE(2, exr2, mr2)
    PART_STORE(3, exr3, mr3)
#undef PART_STORE
}

// colscan: per 64-bucket tile: bstart (global prefix of btot) and
// gsub[s][b] = bstart[b] + sum_{s'<s} cnt[s'][b]  (written [slab][bucket]).
__global__ __launch_bounds__(512) void colscan_kernel(const unsigned* __restrict__ meta_sb,
                                                      const int* __restrict__ btot,
                                                      unsigned* __restrict__ gsub,
                                                      int* __restrict__ bstart) {
    __shared__ int wpart[8][64];
    __shared__ int wred[8];
    __shared__ int bst[64];
    int b0 = blockIdx.x * 64;
    int tid = threadIdx.x, lane = tid & 63, w = tid >> 6;
    int nb = NB - b0; if (nb > 64) nb = 64;

    // base = sum btot[0..b0)
    int part = 0;
    for (int i = tid; i < b0; i += 512) part += btot[i];
#pragma unroll
    for (int off = 32; off > 0; off >>= 1) part += __shfl_down(part, off, 64);
    if (lane == 0) wred[w] = part;
    __syncthreads();
    if (tid == 0) {
        int s_ = 0;
        for (int i = 0; i < 8; ++i) s_ += wred[i];
        wred[0] = s_;
    }
    __syncthreads();
    int baseS = wred[0];

    // exclusive scan of this tile's btot (wave 0)
    if (w == 0) {
        int v = (lane < nb) ? btot[b0 + lane] : 0;
        int incl = v;
#pragma unroll
        for (int off = 1; off < 64; off <<= 1) {
            int u = __shfl_up(incl, off, 64);
            if (lane >= off) incl += u;
        }
        if (lane < nb) {
            int ex = baseS + incl - v;
            bst[lane] = ex;
            bstart[b0 + lane] = ex;
            if (b0 + lane == NB - 1) bstart[NB] = baseS + incl;
        }
    }
    __syncthreads();

    // wave w: slabs [w*64, w*64+64); lane = bucket j
    int j = lane;
    int csum = 0;
    if (j < nb) {
        for (int s = w * 64; s < w * 64 + 64; ++s)
            csum += (int)(meta_sb[(size_t)s * NB + b0 + j] >> 16);
    }
    wpart[w][lane] = csum;
    __syncthreads();
    if (j < nb) {
        int run = bst[j];
        for (int w2 = 0; w2 < w; ++w2) run += wpart[w2][j];
#pragma unroll 4
        for (int s = w * 64; s < w * 64 + 64; ++s) {
            unsigned mv = meta_sb[(size_t)s * NB + b0 + j];
            gsub[(size_t)s * NB + b0 + j] = (unsigned)run;
            run += (int)(mv >> 16);
        }
    }
}

// compact: slab block copies its bucket-runs to global bucket-major edata2.
// XCD swizzle: concurrent same-XCD slabs write adjacent sub-runs -> L2 merge.
__global__ __launch_bounds__(512) void compact_kernel(const unsigned* __restrict__ meta_sb,
                                                      const unsigned* __restrict__ gsub,
                                                      const int2* __restrict__ edata,
                                                      int2* __restrict__ edata2,
                                                      int slab_e) {
    int s = blockIdx.x;
    s = (s & 7) * 64 + (s >> 3);   // bijective: 512 = 8*64
    int tid = threadIdx.x;
    int e0 = s * slab_e;
    for (int b = tid; b < NB; b += 512) {
        unsigned mv = meta_sb[(size_t)s * NB + b];
        int off = (int)(mv & 0xFFFFu);
        int cnt = (int)(mv >> 16);
        unsigned g = gsub[(size_t)s * NB + b];
        const int2* sp = edata + e0 + off;
        int2* dp = edata2 + g;
        for (int i = 0; i < cnt; ++i) dp[i] = sp[i];
    }
}

// aggregate: one 512-thread block per bucket (32 dsts), XCD-swizzled.
// pass1 is now ONE coalesced stream read of the bucket's contiguous region.
__global__ __launch_bounds__(512) void aggregate_kernel(const int* __restrict__ bstart,
                                                        const int2* __restrict__ edata2,
                                                        const __half* __restrict__ z16,
                                                        float* __restrict__ out) {
    __shared__ int2 sbuf[CAPS];
    __shared__ int2 sorted[CAPP];
    __shared__ float dden[32];
    __shared__ int dcnt[32];
    __shared__ int dbase[33];

    int orig = blockIdx.x;
    {
        const int nwg = NB, nx = 8;
        int q = nwg / nx, r = nwg % nx;
        int xcd = orig % nx, idx = orig / nx;
        orig = (xcd < r) ? xcd * (q + 1) + idx : r * (q + 1) + (xcd - r) * q + idx;
    }
    int b = orig;
    int tid = threadIdx.x;
    int lane = tid & 63;
    int wv = tid >> 6;

    int g0 = bstart[b];
    int n = bstart[b + 1] - g0;
    if (n > CAPS) n = CAPS;   // statistically impossible; avoid corruption

    if (tid < 32) { dden[tid] = 0.0f; dcnt[tid] = 0; }
    for (int i = tid; i < CAPP; i += 512) sorted[i] = make_int2(0, 0);
    __syncthreads();

    // pass1: coalesced stream + per-dst count/den
    for (int k = tid; k < n; k += 512) {
        int2 e = edata2[g0 + k];
        sbuf[k] = e;
        int d5 = (e.y >> 16) & 31;
        atomicAdd(&dcnt[d5], 1);
        atomicAdd(&dden[d5], __int_as_float(e.x));
    }
    __syncthreads();

    // per-dst PADDED exclusive scan; dcnt becomes the scatter cursor
    if (tid < 32) {
        int v = dcnt[tid];
        int pv = (v + 31) & ~31;
        int iv = pv;
#pragma unroll
        for (int off = 1; off < 32; off <<= 1) {
            int u = __shfl_up(iv, off, 64);
            if (tid >= off) iv += u;
        }
        dbase[tid + 1] = iv;
        dcnt[tid] = iv - pv;
        if (tid == 0) dbase[0] = 0;
    }
    __syncthreads();

    // counting-sort into padded sorted[]
    for (int k = tid; k < n; k += 512) {
        int2 e = sbuf[k];
        int d5 = (e.y >> 16) & 31;
        int pos = atomicAdd(&dcnt[d5], 1);
        if (pos < CAPP) sorted[pos] = e;
    }
    __syncthreads();

    // main: 8 waves x 4 dsts; padded wide-gather (4 edge-slots x 16 dim-slices)
    int qg = lane >> 4;
    int dl = lane & 15;
    const unsigned short* z16u = (const unsigned short*)z16;
    for (int q = 0; q < 4; ++q) {
        int d5 = wv * 4 + q;
        int d = b * 32 + d5;
        if (d >= NW_) continue;
        int a0 = dbase[d5];
        int npad = dbase[d5 + 1] - a0;
        float dn = dden[d5];
        float invdn = (dn > 0.0f) ? 1.0f / dn : 0.0f;
        float c0 = 0.f, c1 = 0.f, c2 = 0.f, c3 = 0.f;
        for (int j = 0; j < npad; j += 32) {
            int2 ee[8];
#pragma unroll
            for (int u = 0; u < 8; ++u) ee[u] = sorted[a0 + j + u * 4 + qg];
            uint2 zz[8];
#pragma unroll
            for (int u = 0; u < 8; ++u) {
                int srcr = ee[u].y & 0xFFFF;
                zz[u] = *(const uint2*)(z16u + (size_t)srcr * 64 + dl * 4);
            }
#pragma unroll
            for (int u = 0; u < 8; ++u) {
                float ex = __int_as_float(ee[u].x);
                __half2 p0 = *(__half2*)&zz[u].x;
                __half2 p1 = *(__half2*)&zz[u].y;
                c0 = fmaf(ex, __low2float(p0), c0);
                c1 = fmaf(ex, __high2float(p0), c1);
                c2 = fmaf(ex, __low2float(p1), c2);
                c3 = fmaf(ex, __high2float(p1), c3);
            }
        }
        c0 += __shfl_xor(c0, 16, 64); c1 += __shfl_xor(c1, 16, 64);
        c2 += __shfl_xor(c2, 16, 64); c3 += __shfl_xor(c3, 16, 64);
        c0 += __shfl_xor(c0, 32, 64); c1 += __shfl_xor(c1, 32, 64);
        c2 += __shfl_xor(c2, 32, 64); c3 += __shfl_xor(c3, 32, 64);
        if (lane < 16) {
            float4 st = make_float4(c0 * invdn, c1 * invdn, c2 * invdn, c3 * invdn);
            *(float4*)(out + (size_t)d * OUT_DIM_ + lane * 4) = st;
        }
    }
}

extern "C" void kernel_launch(void* const* d_in, const int* in_sizes, int n_in,
                              void* d_out, int out_size, void* d_ws, size_t ws_size,
                              hipStream_t stream) {
    const float* h      = (const float*)d_in[0];
    const float* Wfc    = (const float*)d_in[1];
    const float* w_attn = (const float*)d_in[2];
    const float* weight = (const float*)d_in[3];
    const int*   src    = (const int*)d_in[4];
    const int*   dst    = (const int*)d_in[5];
    int E = in_sizes[3];
    float* out = (float*)d_out;

    int slab_e = (E + NSLAB - 1) / NSLAB;  // 3125 for E=1.6M (must be <= 4096)

    // workspace: edata | edata2 | z16 | t | meta | gsub | btot | bstart | W16f | wv128
    int2*     edata  = (int2*)d_ws;                                 // E
    int2*     edata2 = edata + (size_t)E;                           // E
    __half*   z16    = (__half*)(edata2 + (size_t)E);               // NS*64
    float*    t      = (float*)(z16 + (size_t)NS_ * OUT_DIM_);      // NS
    unsigned* meta   = (unsigned*)(t + NS_);                        // NSLAB*NB
    unsigned* gsub   = meta + (size_t)NSLAB * NB;                   // NSLAB*NB
    int*      btot   = (int*)(gsub + (size_t)NSLAB * NB);           // NB
    int*      bstart = btot + NB;                                   // NB+1
    __half*   W16f   = (__half*)(bstart + NB + 1);                  // 8192
    float*    wv128  = (float*)(W16f + 8192);                       // 128

    hipMemsetAsync(btot, 0, (size_t)NB * sizeof(int), stream);

    prep_kernel<<<1, 256, 0, stream>>>(Wfc, w_attn, W16f, wv128);

    fc_kernel<<<(NS_ + 63) / 64, 256, 0, stream>>>(h, W16f, wv128, z16, t);

    partition_kernel<<<NSLAB, 1024, 0, stream>>>(weight, src, dst, t, meta, btot, edata, E, slab_e);

    colscan_kernel<<<(NB + 63) / 64, 512, 0, stream>>>(meta, btot, gsub, bstart);

    compact_kernel<<<NSLAB, 512, 0, stream>>>(meta, gsub, edata, edata2, slab_e);

    aggregate_kernel<<<NB, 512, 0, stream>>>(bstart, edata2, z16, out);
}

// Round 16
// 83.024 us; speedup vs baseline: 1.5466x; 1.5466x over previous
//
#include <hip/hip_runtime.h>
#include <hip/hip_fp16.h>
#include <math.h>

#define NS_ 50000
#define NW_ 50000
#define IN_DIM_ 128
#define OUT_DIM_ 64

#define NSLAB 512          // partition slabs; slab_e = 3125 for E=1.6M
#define NB 1563            // buckets = ceil(NW/32), bucket = dst >> 5
#define CAPS 1280          // staging capacity (mean 1024, +8 sigma; verified R11-R15)
#define CAPP 2304          // padded sorted capacity

typedef _Float16 h16x8 __attribute__((ext_vector_type(8)));
typedef float f32x4 __attribute__((ext_vector_type(4)));

__device__ inline float leaky01(float x) { return x > 0.0f ? x : 0.01f * x; }

// Pack W into fp16 B-frag order (global, L2-resident) and wv128 = W @ wa.
__global__ __launch_bounds__(256) void prep_kernel(const float* __restrict__ Wfc,
                                                   const float* __restrict__ w_attn,
                                                   __half* __restrict__ W16f,
                                                   float* __restrict__ wv128) {
    int tid = threadIdx.x;
    for (int i = tid; i < IN_DIM_ * OUT_DIM_; i += 256) {
        int k = i >> 6, c = i & 63;
        int ni = c >> 4, c16 = c & 15, kstep = k >> 5, ks = (k & 31) >> 3, el = k & 7;
        W16f[(((ni * 4 + kstep) * 64) + ks * 16 + c16) * 8 + el] = __float2half(Wfc[i]);
    }
    if (tid < IN_DIM_) {
        float s = 0.f;
        for (int c = 0; c < OUT_DIM_; ++c) s += Wfc[tid * OUT_DIM_ + c] * w_attn[c];
        wv128[tid] = s;
    }
}

// MFMA fc: 64 rows/block, 4 waves (verified R14).
__global__ __launch_bounds__(256) void fc_kernel(const float* __restrict__ h,
                                                 const __half* __restrict__ W16f,
                                                 const float* __restrict__ wv128,
                                                 __half* __restrict__ z16,
                                                 float* __restrict__ t) {
    __shared__ __align__(16) __half Afrag[8192];
    __shared__ float ztile[64][68];
    int tid = threadIdx.x;
    int lane = tid & 63;
    int wv = tid >> 6;
    int row0 = blockIdx.x * 64;

    int k0 = (tid & 31) * 4;
    float4 wvv = *(const float4*)(wv128 + k0);
    int kstep = k0 >> 5, ks = (k0 & 31) >> 3, el = k0 & 7;
#pragma unroll
    for (int iter = 0; iter < 8; ++iter) {
        int r = (tid >> 5) + iter * 8;
        int row = row0 + r;
        float4 hv = (row < NS_) ? *(const float4*)(h + (size_t)row * IN_DIM_ + k0)
                                : make_float4(0.f, 0.f, 0.f, 0.f);
        int slot = ((r >> 4) * 4 + kstep) * 64 + ks * 16 + (r & 15);
        int slw = slot ^ ((slot >> 4) & 7);
        __half2 lo = __floats2half2_rn(hv.x, hv.y);
        __half2 hi = __floats2half2_rn(hv.z, hv.w);
        uint2 pk = make_uint2(*(unsigned*)&lo, *(unsigned*)&hi);
        *(uint2*)(&Afrag[slw * 8 + el]) = pk;
        float pt = hv.x * wvv.x + hv.y * wvv.y + hv.z * wvv.z + hv.w * wvv.w;
        pt += __shfl_down(pt, 16, 64);
        pt += __shfl_down(pt, 8, 64);
        pt += __shfl_down(pt, 4, 64);
        pt += __shfl_down(pt, 2, 64);
        pt += __shfl_down(pt, 1, 64);
        if ((tid & 31) == 0 && row < NS_) t[row] = pt;
    }
    __syncthreads();

    h16x8 af[4];
#pragma unroll
    for (int kst = 0; kst < 4; ++kst) {
        int s = (wv * 4 + kst) * 64 + lane;
        int sr = s ^ ((s >> 4) & 7);
        af[kst] = *(const h16x8*)(&Afrag[sr * 8]);
    }
#pragma unroll
    for (int ni = 0; ni < 4; ++ni) {
        f32x4 acc = {0.f, 0.f, 0.f, 0.f};
#pragma unroll
        for (int kst = 0; kst < 4; ++kst) {
            h16x8 bf = *(const h16x8*)(W16f + ((size_t)(ni * 4 + kst) * 64 + lane) * 8);
            acc = __builtin_amdgcn_mfma_f32_16x16x32_f16(af[kst], bf, acc, 0, 0, 0);
        }
        int col = ni * 16 + (lane & 15);
        int rb = wv * 16 + (lane >> 4) * 4;
        ztile[rb + 0][col] = acc[0];
        ztile[rb + 1][col] = acc[1];
        ztile[rb + 2][col] = acc[2];
        ztile[rb + 3][col] = acc[3];
    }
    __syncthreads();

    int nrows = NS_ - row0; if (nrows > 64) nrows = 64;
    for (int j = tid; j < 64 * 32; j += 256) {
        int r = j >> 5, c0 = (j & 31) * 2;
        if (r < nrows) {
            __half2 hp = __floats2half2_rn(ztile[r][c0], ztile[r][c0 + 1]);
            *(__half2*)(z16 + (size_t)(row0 + r) * OUT_DIM_ + c0) = hp;
        }
    }
}

// One 1024-thread block per slab, single pass over edges; two-level wave scan.
// Metadata packed (cnt<<16)|off, written [slab][bucket] (coalesced).
__global__ __launch_bounds__(1024) void partition_kernel(const float* __restrict__ weight,
                                                         const int* __restrict__ src,
                                                         const int* __restrict__ dst,
                                                         const float* __restrict__ t,
                                                         unsigned* __restrict__ meta_sb,
                                                         int2* __restrict__ edata,
                                                         int E, int slab_e) {
    __shared__ int hist[NB];
    __shared__ int cur[NB];
    __shared__ int wsum[16];
    int tid = threadIdx.x;
    int lane = tid & 63;
    int wv = tid >> 6;
    int s = blockIdx.x;
    int e0 = s * slab_e;
    int e1 = e0 + slab_e; if (e1 > E) e1 = E;
    int cnt = e1 - e0;

    for (int i = tid; i < NB; i += 1024) hist[i] = 0;
    __syncthreads();

    float exr0 = 0, exr1 = 0, exr2 = 0, exr3 = 0;
    int mr0 = 0, mr1 = 0, mr2 = 0, mr3 = 0;
#define PART_LOAD(P, EXR, MR)                                              \
    {                                                                      \
        int i = tid + (P) * 1024;                                          \
        if (i < cnt) {                                                     \
            int e = e0 + i;                                                \
            int sr = src[e];                                               \
            int d = dst[e];                                                \
            float ev = weight[e] * leaky01(t[sr]);                         \
            EXR = __expf(ev);                                              \
            MR = sr | ((d & 31) << 16) | ((d >> 5) << 21);                 \
            atomicAdd(&hist[d >> 5], 1);                                   \
        }                                                                  \
    }
    PART_LOAD(0, exr0, mr0)
    PART_LOAD(1, exr1, mr1)
    PART_LOAD(2, exr2, mr2)
    PART_LOAD(3, exr3, mr3)
#undef PART_LOAD
    __syncthreads();

    int i0 = 2 * tid, i1 = 2 * tid + 1;
    int h0 = (i0 < NB) ? hist[i0] : 0;
    int h1 = (i1 < NB) ? hist[i1] : 0;
    int pairv = h0 + h1;
    int incl = pairv;
#pragma unroll
    for (int off = 1; off < 64; off <<= 1) {
        int u = __shfl_up(incl, off, 64);
        if (lane >= off) incl += u;
    }
    if (lane == 63) wsum[wv] = incl;
    __syncthreads();
    int woff = 0;
    for (int w = 0; w < wv; ++w) woff += wsum[w];
    incl += woff;
    int base = incl - pairv;
    if (i0 < NB) {
        cur[i0] = base;
        meta_sb[(size_t)s * NB + i0] = ((unsigned)h0 << 16) | (unsigned)base;
    }
    if (i1 < NB) {
        int b1 = base + h0;
        cur[i1] = b1;
        meta_sb[(size_t)s * NB + i1] = ((unsigned)h1 << 16) | (unsigned)b1;
    }
    __syncthreads();

#define PART_STORE(P, EXR, MR)                                             \
    {                                                                      \
        int i = tid + (P) * 1024;                                          \
        if (i < cnt) {                                                     \
            int b = ((unsigned)MR) >> 21;                                  \
            int pos = atomicAdd(&cur[b], 1);                               \
            edata[e0 + pos] = make_int2(__float_as_int(EXR), MR & 0x1FFFFF); \
        }                                                                  \
    }
    PART_STORE(0, exr0, mr0)
    PART_STORE(1, exr1, mr1)
    PART_STORE(2, exr2, mr2)
    PART_STORE(3, exr3, mr3)
#undef PART_STORE
}

// Tiled transpose of meta [slab][bucket] -> metaT [bucket][slab]
__global__ __launch_bounds__(256) void meta_transpose_kernel(const unsigned* __restrict__ meta,
                                                             unsigned* __restrict__ metaT) {
    __shared__ unsigned tile[64][65];
    int b0 = blockIdx.x * 64;
    int s0 = blockIdx.y * 64;
    int tx = threadIdx.x & 63, ty = threadIdx.x >> 6;
    for (int r = ty; r < 64; r += 4) {
        int b = b0 + tx;
        tile[r][tx] = (b < NB) ? meta[(size_t)(s0 + r) * NB + b] : 0u;
    }
    __syncthreads();
    for (int r = ty; r < 64; r += 4) {
        int b = b0 + r;
        if (b < NB) metaT[(size_t)b * NSLAB + s0 + tx] = tile[tx][r];
    }
}

// One 512-thread block per bucket (32 dsts), XCD-swizzled; padded sorted runs.
// R16: den computed post-sort per wave (lane-parallel + shfl) -- no float LDS
// atomics in pass1 (only the int dcnt count remains).
__global__ __launch_bounds__(512) void aggregate_kernel(const unsigned* __restrict__ metaT,
                                                        const int2* __restrict__ edata,
                                                        const __half* __restrict__ z16,
                                                        float* __restrict__ out,
                                                        int slab_e) {
    __shared__ int2 sbuf[CAPS];
    __shared__ int2 sorted[CAPP];
    __shared__ unsigned short soff[NSLAB];
    __shared__ int arr[NSLAB + 1];
    __shared__ int wsum[8];
    __shared__ int dcnt[32];              // counts, then scatter cursor
    __shared__ int dreal[32];             // real (unpadded) per-dst counts
    __shared__ int dbase[33];             // padded starts

    int orig = blockIdx.x;
    {
        const int nwg = NB, nx = 8;
        int q = nwg / nx, r = nwg % nx;
        int xcd = orig % nx, idx = orig / nx;
        orig = (xcd < r) ? xcd * (q + 1) + idx : r * (q + 1) + (xcd - r) * q + idx;
    }
    int b = orig;
    int tid = threadIdx.x;
    int lane = tid & 63;
    int wv = tid >> 6;

    int cntv;
    {
        unsigned mv = metaT[(size_t)b * NSLAB + tid];
        soff[tid] = (unsigned short)(mv & 0xFFFFu);
        cntv = (int)(mv >> 16);
    }
    if (tid < 32) dcnt[tid] = 0;
    for (int i = tid; i < CAPP; i += 512) sorted[i] = make_int2(0, 0);

    int incl = cntv;
#pragma unroll
    for (int off = 1; off < 64; off <<= 1) {
        int u = __shfl_up(incl, off, 64);
        if (lane >= off) incl += u;
    }
    if (lane == 63) wsum[wv] = incl;
    __syncthreads();
    int woff = 0;
    for (int w = 0; w < wv; ++w) woff += wsum[w];
    incl += woff;
    arr[tid + 1] = incl;
    if (tid == 0) arr[0] = 0;
    __syncthreads();

    int total = arr[NSLAB];
    if (total > CAPS) total = CAPS;

    // pass1: copy segments + per-dst count (int atomic only)
    int gid = tid >> 1, l2 = tid & 1;
    for (int s = gid; s < NSLAB; s += 256) {
        int base = arr[s];
        int len = arr[s + 1] - base;
        int so = (int)soff[s];
        for (int j = l2; j < len; j += 2) {
            int p = base + j;
            if (p < CAPS) {
                int2 e = edata[(size_t)s * slab_e + so + j];
                sbuf[p] = e;
                atomicAdd(&dcnt[(e.y >> 16) & 31], 1);
            }
        }
    }
    __syncthreads();

    // per-dst PADDED exclusive scan; save real counts; dcnt becomes cursor
    if (tid < 32) {
        int v = dcnt[tid];
        dreal[tid] = v;
        int pv = (v + 31) & ~31;
        int iv = pv;
#pragma unroll
        for (int off = 1; off < 32; off <<= 1) {
            int u = __shfl_up(iv, off, 64);
            if (tid >= off) iv += u;
        }
        dbase[tid + 1] = iv;
        dcnt[tid] = iv - pv;
        if (tid == 0) dbase[0] = 0;
    }
    __syncthreads();

    // pass2: counting-sort payloads into padded sorted[]
    for (int k = tid; k < total; k += 512) {
        int2 e = sbuf[k];
        int d5 = (e.y >> 16) & 31;
        int pos = atomicAdd(&dcnt[d5], 1);
        if (pos < CAPP) sorted[pos] = e;
    }
    __syncthreads();

    // main: 8 waves x 4 dsts; per-dst den via lane-parallel sum, then
    // padded wide-gather loop (4 edge-slots x 16 dim-slices, uint2)
    int qg = lane >> 4;
    int dl = lane & 15;
    const unsigned short* z16u = (const unsigned short*)z16;
    for (int q = 0; q < 4; ++q) {
        int d5 = wv * 4 + q;
        int d = b * 32 + d5;
        if (d >= NW_) continue;
        int a0 = dbase[d5];
        int npad = dbase[d5 + 1] - a0;
        int v = dreal[d5];

        // den = sum of ex over the real run [a0, a0+v)
        float den = 0.0f;
        for (int i = lane; i < v; i += 64) den += __int_as_float(sorted[a0 + i].x);
#pragma unroll
        for (int off = 32; off > 0; off >>= 1) den += __shfl_xor(den, off, 64);
        float invdn = (v > 0) ? 1.0f / den : 0.0f;

        float c0 = 0.f, c1 = 0.f, c2 = 0.f, c3 = 0.f;
        for (int j = 0; j < npad; j += 32) {
            int2 ee[8];
#pragma unroll
            for (int u = 0; u < 8; ++u) ee[u] = sorted[a0 + j + u * 4 + qg];
            uint2 zz[8];
#pragma unroll
            for (int u = 0; u < 8; ++u) {
                int srcr = ee[u].y & 0xFFFF;
                zz[u] = *(const uint2*)(z16u + (size_t)srcr * 64 + dl * 4);
            }
#pragma unroll
            for (int u = 0; u < 8; ++u) {
                float ex = __int_as_float(ee[u].x);
                __half2 p0 = *(__half2*)&zz[u].x;
                __half2 p1 = *(__half2*)&zz[u].y;
                c0 = fmaf(ex, __low2float(p0), c0);
                c1 = fmaf(ex, __high2float(p0), c1);
                c2 = fmaf(ex, __low2float(p1), c2);
                c3 = fmaf(ex, __high2float(p1), c3);
            }
        }
        c0 += __shfl_xor(c0, 16, 64); c1 += __shfl_xor(c1, 16, 64);
        c2 += __shfl_xor(c2, 16, 64); c3 += __shfl_xor(c3, 16, 64);
        c0 += __shfl_xor(c0, 32, 64); c1 += __shfl_xor(c1, 32, 64);
        c2 += __shfl_xor(c2, 32, 64); c3 += __shfl_xor(c3, 32, 64);
        if (lane < 16) {
            float4 st = make_float4(c0 * invdn, c1 * invdn, c2 * invdn, c3 * invdn);
            *(float4*)(out + (size_t)d * OUT_DIM_ + lane * 4) = st;
        }
    }
}

extern "C" void kernel_launch(void* const* d_in, const int* in_sizes, int n_in,
                              void* d_out, int out_size, void* d_ws, size_t ws_size,
                              hipStream_t stream) {
    const float* h      = (const float*)d_in[0];
    const float* Wfc    = (const float*)d_in[1];
    const float* w_attn = (const float*)d_in[2];
    const float* weight = (const float*)d_in[3];
    const int*   src    = (const int*)d_in[4];
    const int*   dst    = (const int*)d_in[5];
    int E = in_sizes[3];
    float* out = (float*)d_out;

    int slab_e = (E + NSLAB - 1) / NSLAB;  // 3125 for E=1.6M (must be <= 4096)

    // workspace: edata | z16 | t | meta | metaT | W16f | wv128
    int2*     edata = (int2*)d_ws;                                  // E
    __half*   z16   = (__half*)(edata + (size_t)E);                 // NS*64
    float*    t     = (float*)(z16 + (size_t)NS_ * OUT_DIM_);       // NS
    unsigned* meta  = (unsigned*)(t + NS_);                         // NSLAB*NB
    unsigned* metaT = meta + (size_t)NSLAB * NB;                    // NB*NSLAB
    __half*   W16f  = (__half*)(metaT + (size_t)NSLAB * NB);        // 8192
    float*    wv128 = (float*)(W16f + 8192);                        // 128

    prep_kernel<<<1, 256, 0, stream>>>(Wfc, w_attn, W16f, wv128);

    fc_kernel<<<(NS_ + 63) / 64, 256, 0, stream>>>(h, W16f, wv128, z16, t);

    partition_kernel<<<NSLAB, 1024, 0, stream>>>(weight, src, dst, t, meta, edata, E, slab_e);

    dim3 tg((NB + 63) / 64, NSLAB / 64);
    meta_transpose_kernel<<<tg, 256, 0, stream>>>(meta, metaT);

    aggregate_kernel<<<NB, 512, 0, stream>>>(metaT, edata, z16, out, slab_e);
}